// Round 1
// baseline (1050.263 us; speedup 1.0000x reference)
//
#include <hip/hip_runtime.h>

#define HC 128          // H*C = output dim
#define HEADS 8
#define CPH 16
#define EDIM 16
#define NG 8
#define NEG_SLOPE 0.2f
#define GEPS 1e-5f

// ---------- float <-> ordered-uint encoding for atomicMax on floats ----------
__device__ __forceinline__ unsigned ordf(float f) {
  unsigned u = __float_as_uint(f);
  return (u & 0x80000000u) ? ~u : (u | 0x80000000u);
}
__device__ __forceinline__ float deordf(unsigned u) {
  u = (u & 0x80000000u) ? (u ^ 0x80000000u) : ~u;
  return __uint_as_float(u);
}

// ---------- K0: zero scratch ----------
__global__ void zero_k(float* __restrict__ p, size_t nwords) {
  size_t i = (size_t)blockIdx.x * 256 + threadIdx.x;
  if (i < nwords) p[i] = 0.f;
}

// ---------- K1: degree of real edges (by dst) ----------
__global__ void count_deg(const int* __restrict__ ei, int* __restrict__ deg, int E) {
  int e = blockIdx.x * 256 + threadIdx.x;
  if (e >= E) return;
  atomicAdd(&deg[ei[E + e]], 1);
}

// ---------- K2: y = x @ W + b   (N x 128 @ 128 x 128, fp32) ----------
// block 256 threads: 8 rows x 32 float4-column-groups
__global__ void __launch_bounds__(256) gemm_xw(
    const float* __restrict__ x, const float* __restrict__ W,
    const float* __restrict__ b, float* __restrict__ y, int N) {
  int t = threadIdx.x;
  int c4 = t & 31;          // float4 column group (4 channels)
  int rl = t >> 5;          // 0..7 local row
  long row = (long)blockIdx.x * 8 + rl;
  if (row >= N) return;
  const float4* W4 = (const float4*)W;          // [128][32] of float4
  const float4* x4 = (const float4*)(x + row * HC);
  float4 acc = ((const float4*)b)[c4];
  #pragma unroll 8
  for (int k4 = 0; k4 < 32; ++k4) {
    float4 xv = x4[k4];
    float4 w0 = W4[(k4 * 4 + 0) * 32 + c4];
    float4 w1 = W4[(k4 * 4 + 1) * 32 + c4];
    float4 w2 = W4[(k4 * 4 + 2) * 32 + c4];
    float4 w3 = W4[(k4 * 4 + 3) * 32 + c4];
    acc.x = fmaf(xv.x, w0.x, acc.x); acc.x = fmaf(xv.y, w1.x, acc.x);
    acc.x = fmaf(xv.z, w2.x, acc.x); acc.x = fmaf(xv.w, w3.x, acc.x);
    acc.y = fmaf(xv.x, w0.y, acc.y); acc.y = fmaf(xv.y, w1.y, acc.y);
    acc.y = fmaf(xv.z, w2.y, acc.y); acc.y = fmaf(xv.w, w3.y, acc.y);
    acc.z = fmaf(xv.x, w0.z, acc.z); acc.z = fmaf(xv.y, w1.z, acc.z);
    acc.z = fmaf(xv.z, w2.z, acc.z); acc.z = fmaf(xv.w, w3.z, acc.z);
    acc.w = fmaf(xv.x, w0.w, acc.w); acc.w = fmaf(xv.y, w1.w, acc.w);
    acc.w = fmaf(xv.z, w2.w, acc.w); acc.w = fmaf(xv.w, w3.w, acc.w);
  }
  ((float4*)(y + row * HC))[c4] = acc;
}

// ---------- K5: scan of deg -> offsets (CSR) ----------
__global__ void scan1(const int* __restrict__ deg, int* __restrict__ bsum, int N) {
  __shared__ int s[256];
  int t = threadIdx.x;
  int n = blockIdx.x * 256 + t;
  s[t] = (n < N) ? deg[n] : 0;
  __syncthreads();
  for (int off = 128; off > 0; off >>= 1) {
    if (t < off) s[t] += s[t + off];
    __syncthreads();
  }
  if (t == 0) bsum[blockIdx.x] = s[0];
}
__global__ void scan2(const int* __restrict__ bsum, int* __restrict__ bofs, int nb,
                      int* __restrict__ offsets, int N) {
  int run = 0;
  for (int b = 0; b < nb; ++b) { bofs[b] = run; run += bsum[b]; }
  offsets[N] = run;
}
__global__ void scan3(const int* __restrict__ deg, const int* __restrict__ bofs,
                      int* __restrict__ offsets, int N) {
  __shared__ int s[256];
  int t = threadIdx.x;
  int n = blockIdx.x * 256 + t;
  int v = (n < N) ? deg[n] : 0;
  s[t] = v;
  __syncthreads();
  for (int off = 1; off < 256; off <<= 1) {
    int add = (t >= off) ? s[t - off] : 0;
    __syncthreads();
    s[t] += add;
    __syncthreads();
  }
  if (n < N) offsets[n] = bofs[blockIdx.x] + s[t] - v;  // exclusive
}

// ---------- K6: fill CSR edge ids ----------
__global__ void fill_csr(const int* __restrict__ ei, int* __restrict__ cursor,
                         const int* __restrict__ offsets, int* __restrict__ csr, int E) {
  int e = blockIdx.x * 256 + threadIdx.x;
  if (e >= E) return;
  int d = ei[E + e];
  int pos = atomicAdd(&cursor[d], 1);
  csr[offsets[d] + pos] = e;
}

// ---------- K3a: ea_mean per node ----------
// 256 threads = 16 nodes x 16 lanes (one lane per edge-feature)
__global__ void __launch_bounds__(256) ea_mean_k(
    const int* __restrict__ offsets, const int* __restrict__ csr,
    const float* __restrict__ ea, float* __restrict__ ea_mean, int N) {
  int t = threadIdx.x;
  int k = t & 15;
  int grp = t >> 4;
  int n = blockIdx.x * 16 + grp;
  if (n >= N) return;
  int j0 = offsets[n], j1 = offsets[n + 1];
  float sum = 0.f;
  for (int j = j0; j < j1; ++j) {
    int e = csr[j];
    sum += ea[(long)e * EDIM + k];
  }
  float d = (float)(j1 - j0);
  if (d < 1.f) d = 1.f;
  ea_mean[(long)n * EDIM + k] = sum / d;
}

// ---------- K3b: self-loop attention logits + emax init ----------
// 256 threads = 2 groups of 128 channels; each group does 8 nodes
__global__ void __launch_bounds__(256) selfloop_attn(
    const float* __restrict__ xl, const float* __restrict__ xr,
    const float* __restrict__ ea_mean, const float* __restrict__ We,
    const float* __restrict__ att, float* __restrict__ e_buf,
    unsigned* __restrict__ emax, int N, int E) {
  int t = threadIdx.x;
  int ch = t & 127;
  int g2 = t >> 7;
  float we[EDIM];
  #pragma unroll
  for (int k = 0; k < EDIM; ++k) we[k] = We[k * HC + ch];
  float av = att[ch];
  int h = ch >> 4;
  long base = (long)blockIdx.x * 16 + g2 * 8;
  for (int it = 0; it < 8; ++it) {
    long n = base + it;
    if (n >= N) return;
    const float* eap = ea_mean + n * EDIM;
    float ee = 0.f;
    #pragma unroll
    for (int k = 0; k < EDIM; ++k) ee = fmaf(eap[k], we[k], ee);
    float m = xl[n * HC + ch] + xr[n * HC + ch] + ee;
    m = m > 0.f ? m : NEG_SLOPE * m;
    float p = m * av;
    p += __shfl_xor(p, 8);
    p += __shfl_xor(p, 4);
    p += __shfl_xor(p, 2);
    p += __shfl_xor(p, 1);
    if ((ch & 15) == 0) {
      e_buf[(long)(E + n) * HEADS + h] = p;
      emax[n * HEADS + h] = ordf(p);   // plain store: self-loop is the init
    }
  }
}

// ---------- K4: real-edge attention logits + segment max ----------
__global__ void __launch_bounds__(256) edge_attn(
    const int* __restrict__ ei, const float* __restrict__ ea,
    const float* __restrict__ xl, const float* __restrict__ xr,
    const float* __restrict__ We, const float* __restrict__ att,
    float* __restrict__ e_buf, unsigned* __restrict__ emax, int E) {
  int t = threadIdx.x;
  int ch = t & 127;
  int g2 = t >> 7;
  float we[EDIM];
  #pragma unroll
  for (int k = 0; k < EDIM; ++k) we[k] = We[k * HC + ch];
  float av = att[ch];
  int h = ch >> 4;
  long base = (long)blockIdx.x * 16 + g2 * 8;
  for (int it = 0; it < 8; ++it) {
    long e = base + it;
    if (e >= E) return;
    int s = ei[e];
    int d = ei[E + e];
    const float* eap = ea + e * EDIM;
    float ee = 0.f;
    #pragma unroll
    for (int k = 0; k < EDIM; ++k) ee = fmaf(eap[k], we[k], ee);
    float m = xl[(long)s * HC + ch] + xr[(long)d * HC + ch] + ee;
    m = m > 0.f ? m : NEG_SLOPE * m;
    float p = m * av;
    p += __shfl_xor(p, 8);
    p += __shfl_xor(p, 4);
    p += __shfl_xor(p, 2);
    p += __shfl_xor(p, 1);
    if ((ch & 15) == 0) {
      e_buf[e * HEADS + h] = p;
      atomicMax(&emax[(long)d * HEADS + h], ordf(p));
    }
  }
}

// ---------- K6.5: logits -> exp(logit - segmax) in place ----------
__global__ void exp_k(const int* __restrict__ ei, const unsigned* __restrict__ emax,
                      float* __restrict__ e_buf, int E, int N) {
  long i = (long)blockIdx.x * 256 + threadIdx.x;
  long tot = (long)(E + N) * HEADS;
  if (i >= tot) return;
  long e = i >> 3;
  int h = (int)(i & 7);
  int d = (e < E) ? ei[E + e] : (int)(e - E);
  float mx = deordf(emax[(long)d * HEADS + h]);
  e_buf[i] = expf(e_buf[i] - mx);
}

// ---------- K7: per-node softmax-weighted aggregation + bias + residual ----------
__global__ void __launch_bounds__(128) aggregate(
    const int* __restrict__ offsets, const int* __restrict__ csr,
    const int* __restrict__ ei, const float* __restrict__ e_buf,
    const float* __restrict__ xl, const float* __restrict__ x,
    const float* __restrict__ bias, float* __restrict__ out, int N, int E) {
  int ch = threadIdx.x;
  long n = blockIdx.x;
  int h = ch >> 4;
  // self loop
  float w = e_buf[(long)(E + n) * HEADS + h];
  float den = w;
  float acc = w * xl[n * HC + ch];
  int j0 = offsets[n], j1 = offsets[n + 1];
  for (int j = j0; j < j1; ++j) {
    int e = csr[j];
    float we = e_buf[(long)e * HEADS + h];
    int s = ei[e];
    acc = fmaf(we, xl[(long)s * HC + ch], acc);
    den += we;
  }
  out[n * HC + ch] = acc / den + bias[ch] + x[n * HC + ch];
}

// ---------- K8: GraphNorm segment sums (batch is sorted) ----------
__global__ void __launch_bounds__(128) gn_stats(
    const float* __restrict__ out, const int* __restrict__ batch,
    float* __restrict__ gsum, float* __restrict__ gsq, int* __restrict__ gcnt, int N) {
  int ch = threadIdx.x;
  int n0 = blockIdx.x * 128;
  int cur = -1;
  float sum = 0.f, sq = 0.f;
  int cnt = 0;
  for (int i = 0; i < 128; ++i) {
    int n = n0 + i;
    if (n >= N) break;
    int g = batch[n];
    if (g != cur) {
      if (cur >= 0) {
        atomicAdd(&gsum[cur * HC + ch], sum);
        atomicAdd(&gsq[cur * HC + ch], sq);
        if (ch == 0) atomicAdd(&gcnt[cur], cnt);
      }
      cur = g; sum = 0.f; sq = 0.f; cnt = 0;
    }
    float v = out[(long)n * HC + ch];
    sum += v; sq += v * v; ++cnt;
  }
  if (cur >= 0) {
    atomicAdd(&gsum[cur * HC + ch], sum);
    atomicAdd(&gsq[cur * HC + ch], sq);
    if (ch == 0) atomicAdd(&gcnt[cur], cnt);
  }
}

// ---------- K9: finalize mean / inv-std ----------
__global__ void gn_finalize(const float* __restrict__ gsum, const float* __restrict__ gsq,
                            const int* __restrict__ gcnt, const float* __restrict__ gms,
                            float* __restrict__ msub, float* __restrict__ istd) {
  int t = blockIdx.x * 256 + threadIdx.x;
  if (t >= NG * HC) return;
  int g = t >> 7, ch = t & 127;
  float cnt = (float)gcnt[g];
  if (cnt < 1.f) cnt = 1.f;
  float mean = gsum[t] / cnt;
  float c = gms[ch] * mean;              // the subtracted constant
  float ex2 = gsq[t] / cnt;
  float var = ex2 - 2.f * c * mean + c * c;   // E[(x-c)^2]
  msub[t] = c;
  istd[t] = rsqrtf(var + GEPS);
}

// ---------- K10: normalize + affine + ELU ----------
__global__ void gn_apply(float* __restrict__ out, const int* __restrict__ batch,
                         const float* __restrict__ msub, const float* __restrict__ istd,
                         const float* __restrict__ gnw, const float* __restrict__ gnb, int N) {
  long i = (long)blockIdx.x * 256 + threadIdx.x;
  if (i >= (long)N * HC) return;
  int ch = (int)(i & 127);
  long n = i >> 7;
  int g = batch[n];
  float v = out[i];
  float sub = v - msub[g * HC + ch];
  float o = fmaf(gnw[ch] * sub, istd[g * HC + ch], gnb[ch]);
  out[i] = o > 0.f ? o : expm1f(o);
}

extern "C" void kernel_launch(void* const* d_in, const int* in_sizes, int n_in,
                              void* d_out, int out_size, void* d_ws, size_t ws_size,
                              hipStream_t stream) {
  const float* x    = (const float*)d_in[0];
  const int*   ei   = (const int*)d_in[1];
  const float* ea   = (const float*)d_in[2];
  const int*   batch= (const int*)d_in[3];
  const float* Wl   = (const float*)d_in[4];
  const float* bl   = (const float*)d_in[5];
  const float* Wr   = (const float*)d_in[6];
  const float* br   = (const float*)d_in[7];
  const float* We   = (const float*)d_in[8];
  const float* att  = (const float*)d_in[9];
  const float* bias = (const float*)d_in[10];
  const float* gnw  = (const float*)d_in[11];
  const float* gnb  = (const float*)d_in[12];
  const float* gms  = (const float*)d_in[13];
  int N = in_sizes[0] / HC;
  int E = in_sizes[2] / EDIM;
  float* out = (float*)d_out;
  (void)n_in; (void)out_size; (void)ws_size;

  // ---- workspace carve-up (4-byte words, 16B aligned blocks) ----
  float* wsf = (float*)d_ws;
  size_t off = 0;
  auto alloc = [&](size_t words) -> float* {
    float* p = wsf + off;
    off += (words + 3) & ~(size_t)3;
    return p;
  };
  int*      deg     = (int*)alloc(N);
  int*      cursor  = (int*)alloc(N);
  int*      gcnt    = (int*)alloc(NG);
  float*    gsum    = alloc(NG * HC);
  float*    gsq     = alloc(NG * HC);
  size_t zero_words = off;                 // everything above starts at 0
  float*    msub    = alloc(NG * HC);
  float*    istd    = alloc(NG * HC);
  int*      bsum    = (int*)alloc(256);
  int*      bofs    = (int*)alloc(256);
  int*      offsets = (int*)alloc((size_t)N + 1);
  float*    ea_mean = alloc((size_t)N * EDIM);
  float*    xl      = alloc((size_t)N * HC);
  float*    xr      = alloc((size_t)N * HC);
  unsigned* emax    = (unsigned*)alloc((size_t)N * HEADS);
  float*    e_buf   = alloc((size_t)(E + N) * HEADS);
  int*      csr     = (int*)alloc(E);

  int nb = (N + 255) / 256;   // scan blocks (<=256 by construction for N<=65536)

  zero_k<<<(unsigned)((zero_words + 255) / 256), 256, 0, stream>>>(wsf, zero_words);
  count_deg<<<(E + 255) / 256, 256, 0, stream>>>(ei, deg, E);
  gemm_xw<<<(N + 7) / 8, 256, 0, stream>>>(x, Wl, bl, xl, N);
  gemm_xw<<<(N + 7) / 8, 256, 0, stream>>>(x, Wr, br, xr, N);
  scan1<<<nb, 256, 0, stream>>>(deg, bsum, N);
  scan2<<<1, 1, 0, stream>>>(bsum, bofs, nb, offsets, N);
  scan3<<<nb, 256, 0, stream>>>(deg, bofs, offsets, N);
  fill_csr<<<(E + 255) / 256, 256, 0, stream>>>(ei, cursor, offsets, csr, E);
  ea_mean_k<<<(N + 15) / 16, 256, 0, stream>>>(offsets, csr, ea, ea_mean, N);
  selfloop_attn<<<(N + 15) / 16, 256, 0, stream>>>(xl, xr, ea_mean, We, att, e_buf, emax, N, E);
  edge_attn<<<(E + 15) / 16, 256, 0, stream>>>(ei, ea, xl, xr, We, att, e_buf, emax, E);
  {
    long tot = (long)(E + N) * HEADS;
    exp_k<<<(unsigned)((tot + 255) / 256), 256, 0, stream>>>(ei, emax, e_buf, E, N);
  }
  aggregate<<<N, 128, 0, stream>>>(offsets, csr, ei, e_buf, xl, x, bias, out, N, E);
  gn_stats<<<(N + 127) / 128, 128, 0, stream>>>(out, batch, gsum, gsq, gcnt, N);
  gn_finalize<<<(NG * HC + 255) / 256, 256, 0, stream>>>(gsum, gsq, gcnt, gms, msub, istd);
  {
    long tot = (long)N * HC;
    gn_apply<<<(unsigned)((tot + 255) / 256), 256, 0, stream>>>(out, batch, msub, istd, gnw, gnb, N);
  }
}

// Round 2
// 635.491 us; speedup vs baseline: 1.6527x; 1.6527x over previous
//
#include <hip/hip_runtime.h>

#define HC 128          // H*C = output dim
#define HEADS 8
#define CPH 16
#define EDIM 16
#define NG 8
#define NEG_SLOPE 0.2f
#define GEPS 1e-5f

// ---------- K0: zero scratch ----------
__global__ void zero_k(float* __restrict__ p, size_t nwords) {
  size_t i = (size_t)blockIdx.x * 256 + threadIdx.x;
  if (i < nwords) p[i] = 0.f;
}

// ---------- K1: degree of real edges (by dst) ----------
__global__ void count_deg(const int* __restrict__ ei, int* __restrict__ deg, int E) {
  int e = blockIdx.x * 256 + threadIdx.x;
  if (e >= E) return;
  atomicAdd(&deg[ei[E + e]], 1);
}

// ---------- K2: y = x @ W + b   (N x 128 @ 128 x 128, fp32) ----------
// block 256 threads: 8 rows x 32 float4-column-groups
__global__ void __launch_bounds__(256) gemm_xw(
    const float* __restrict__ x, const float* __restrict__ W,
    const float* __restrict__ b, float* __restrict__ y, int N) {
  int t = threadIdx.x;
  int c4 = t & 31;          // float4 column group (4 channels)
  int rl = t >> 5;          // 0..7 local row
  long row = (long)blockIdx.x * 8 + rl;
  if (row >= N) return;
  const float4* W4 = (const float4*)W;          // [128][32] of float4
  const float4* x4 = (const float4*)(x + row * HC);
  float4 acc = ((const float4*)b)[c4];
  #pragma unroll 8
  for (int k4 = 0; k4 < 32; ++k4) {
    float4 xv = x4[k4];
    float4 w0 = W4[(k4 * 4 + 0) * 32 + c4];
    float4 w1 = W4[(k4 * 4 + 1) * 32 + c4];
    float4 w2 = W4[(k4 * 4 + 2) * 32 + c4];
    float4 w3 = W4[(k4 * 4 + 3) * 32 + c4];
    acc.x = fmaf(xv.x, w0.x, acc.x); acc.x = fmaf(xv.y, w1.x, acc.x);
    acc.x = fmaf(xv.z, w2.x, acc.x); acc.x = fmaf(xv.w, w3.x, acc.x);
    acc.y = fmaf(xv.x, w0.y, acc.y); acc.y = fmaf(xv.y, w1.y, acc.y);
    acc.y = fmaf(xv.z, w2.y, acc.y); acc.y = fmaf(xv.w, w3.y, acc.y);
    acc.z = fmaf(xv.x, w0.z, acc.z); acc.z = fmaf(xv.y, w1.z, acc.z);
    acc.z = fmaf(xv.z, w2.z, acc.z); acc.z = fmaf(xv.w, w3.z, acc.z);
    acc.w = fmaf(xv.x, w0.w, acc.w); acc.w = fmaf(xv.y, w1.w, acc.w);
    acc.w = fmaf(xv.z, w2.w, acc.w); acc.w = fmaf(xv.w, w3.w, acc.w);
  }
  ((float4*)(y + row * HC))[c4] = acc;
}

// ---------- K3: scan of deg -> offsets (CSR) ----------
__global__ void scan1(const int* __restrict__ deg, int* __restrict__ bsum, int N) {
  __shared__ int s[256];
  int t = threadIdx.x;
  int n = blockIdx.x * 256 + t;
  s[t] = (n < N) ? deg[n] : 0;
  __syncthreads();
  for (int off = 128; off > 0; off >>= 1) {
    if (t < off) s[t] += s[t + off];
    __syncthreads();
  }
  if (t == 0) bsum[blockIdx.x] = s[0];
}
__global__ void scan2(const int* __restrict__ bsum, int* __restrict__ bofs, int nb,
                      int* __restrict__ offsets, int N) {
  int run = 0;
  for (int b = 0; b < nb; ++b) { bofs[b] = run; run += bsum[b]; }
  offsets[N] = run;
}
__global__ void scan3(const int* __restrict__ deg, const int* __restrict__ bofs,
                      int* __restrict__ offsets, int N) {
  __shared__ int s[256];
  int t = threadIdx.x;
  int n = blockIdx.x * 256 + t;
  int v = (n < N) ? deg[n] : 0;
  s[t] = v;
  __syncthreads();
  for (int off = 1; off < 256; off <<= 1) {
    int add = (t >= off) ? s[t - off] : 0;
    __syncthreads();
    s[t] += add;
    __syncthreads();
  }
  if (n < N) offsets[n] = bofs[blockIdx.x] + s[t] - v;  // exclusive
}

// ---------- K4: fill CSR edge ids ----------
__global__ void fill_csr(const int* __restrict__ ei, int* __restrict__ cursor,
                         const int* __restrict__ offsets, int* __restrict__ csr, int E) {
  int e = blockIdx.x * 256 + threadIdx.x;
  if (e >= E) return;
  int d = ei[E + e];
  int pos = atomicAdd(&cursor[d], 1);
  csr[offsets[d] + pos] = e;
}

// ---------- K5: FUSED per-node attention + online softmax + aggregation ----------
// One 128-thread block per destination node. Online softmax over in-edges,
// self-loop (with ea fill_value='mean') merged at the end:
//   ea_mean . We[:,ch] == mean over edges of (ea[e] . We[:,ch]) by linearity.
__global__ void __launch_bounds__(128) fused_node(
    const int* __restrict__ offsets, const int* __restrict__ csr,
    const int* __restrict__ ei, const float* __restrict__ ea,
    const float* __restrict__ xl, const float* __restrict__ xr,
    const float* __restrict__ We, const float* __restrict__ att,
    const float* __restrict__ x, const float* __restrict__ bias,
    float* __restrict__ out, int N, int E) {
  int ch = threadIdx.x;
  long n = blockIdx.x;
  float we[EDIM];
  #pragma unroll
  for (int k = 0; k < EDIM; ++k) we[k] = We[k * HC + ch];
  float av = att[ch];
  float xl_n = xl[n * HC + ch];
  float xr_n = xr[n * HC + ch];
  int j0 = offsets[n], j1 = offsets[n + 1];

  float m = -INFINITY;   // running max per head (uniform across 16-lane group)
  float den = 0.f;       // running softmax denominator
  float acc = 0.f;       // running weighted feature sum (per channel)
  float eesum = 0.f;     // per-channel sum of eev (for self-loop mean)

  for (int j = j0; j < j1; ++j) {
    int e = __builtin_amdgcn_readfirstlane(csr[j]);
    int s = __builtin_amdgcn_readfirstlane(ei[e]);
    float xls = xl[(long)s * HC + ch];
    const float4* eap = (const float4*)(ea + (long)e * EDIM);
    float4 a0 = eap[0], a1 = eap[1], a2 = eap[2], a3 = eap[3];
    float eev = a0.x * we[0];
    eev = fmaf(a0.y, we[1], eev);  eev = fmaf(a0.z, we[2], eev);
    eev = fmaf(a0.w, we[3], eev);  eev = fmaf(a1.x, we[4], eev);
    eev = fmaf(a1.y, we[5], eev);  eev = fmaf(a1.z, we[6], eev);
    eev = fmaf(a1.w, we[7], eev);  eev = fmaf(a2.x, we[8], eev);
    eev = fmaf(a2.y, we[9], eev);  eev = fmaf(a2.z, we[10], eev);
    eev = fmaf(a2.w, we[11], eev); eev = fmaf(a3.x, we[12], eev);
    eev = fmaf(a3.y, we[13], eev); eev = fmaf(a3.z, we[14], eev);
    eev = fmaf(a3.w, we[15], eev);
    eesum += eev;
    float mm = xls + xr_n + eev;
    mm = mm > 0.f ? mm : NEG_SLOPE * mm;
    float p = mm * av;
    p += __shfl_xor(p, 8);
    p += __shfl_xor(p, 4);
    p += __shfl_xor(p, 2);
    p += __shfl_xor(p, 1);          // all 16 lanes of the head hold the logit
    float mn = fmaxf(m, p);
    float sc = __expf(m - mn);
    float w  = __expf(p - mn);
    acc = fmaf(acc, sc, w * xls);
    den = fmaf(den, sc, w);
    m = mn;
  }

  // ---- self-loop ----
  int deg = j1 - j0;
  float ee = eesum / (float)(deg > 0 ? deg : 1);
  float mm = xl_n + xr_n + ee;
  mm = mm > 0.f ? mm : NEG_SLOPE * mm;
  float p = mm * av;
  p += __shfl_xor(p, 8);
  p += __shfl_xor(p, 4);
  p += __shfl_xor(p, 2);
  p += __shfl_xor(p, 1);
  float mn = fmaxf(m, p);
  float sc = __expf(m - mn);
  float w  = __expf(p - mn);
  acc = fmaf(acc, sc, w * xl_n);
  den = fmaf(den, sc, w);

  out[n * HC + ch] = acc / den + bias[ch] + x[n * HC + ch];
}

// ---------- K6: GraphNorm segment sums (batch is sorted) ----------
#define GN_NODES 32
__global__ void __launch_bounds__(128) gn_stats(
    const float* __restrict__ out, const int* __restrict__ batch,
    float* __restrict__ gsum, float* __restrict__ gsq, int* __restrict__ gcnt, int N) {
  int ch = threadIdx.x;
  int n0 = blockIdx.x * GN_NODES;
  int cur = -1;
  float sum = 0.f, sq = 0.f;
  int cnt = 0;
  for (int i = 0; i < GN_NODES; ++i) {
    int n = n0 + i;
    if (n >= N) break;
    int g = batch[n];
    if (g != cur) {
      if (cur >= 0) {
        atomicAdd(&gsum[cur * HC + ch], sum);
        atomicAdd(&gsq[cur * HC + ch], sq);
        if (ch == 0) atomicAdd(&gcnt[cur], cnt);
      }
      cur = g; sum = 0.f; sq = 0.f; cnt = 0;
    }
    float v = out[(long)n * HC + ch];
    sum += v; sq += v * v; ++cnt;
  }
  if (cur >= 0) {
    atomicAdd(&gsum[cur * HC + ch], sum);
    atomicAdd(&gsq[cur * HC + ch], sq);
    if (ch == 0) atomicAdd(&gcnt[cur], cnt);
  }
}

// ---------- K7: finalize mean / inv-std ----------
__global__ void gn_finalize(const float* __restrict__ gsum, const float* __restrict__ gsq,
                            const int* __restrict__ gcnt, const float* __restrict__ gms,
                            float* __restrict__ msub, float* __restrict__ istd) {
  int t = blockIdx.x * 256 + threadIdx.x;
  if (t >= NG * HC) return;
  int g = t >> 7, ch = t & 127;
  float cnt = (float)gcnt[g];
  if (cnt < 1.f) cnt = 1.f;
  float mean = gsum[t] / cnt;
  float c = gms[ch] * mean;              // the subtracted constant
  float ex2 = gsq[t] / cnt;
  float var = ex2 - 2.f * c * mean + c * c;   // E[(x-c)^2]
  msub[t] = c;
  istd[t] = rsqrtf(var + GEPS);
}

// ---------- K8: normalize + affine + ELU ----------
__global__ void gn_apply(float* __restrict__ out, const int* __restrict__ batch,
                         const float* __restrict__ msub, const float* __restrict__ istd,
                         const float* __restrict__ gnw, const float* __restrict__ gnb, int N) {
  long i = (long)blockIdx.x * 256 + threadIdx.x;
  if (i >= (long)N * HC) return;
  int ch = (int)(i & 127);
  long n = i >> 7;
  int g = batch[n];
  float v = out[i];
  float sub = v - msub[g * HC + ch];
  float o = fmaf(gnw[ch] * sub, istd[g * HC + ch], gnb[ch]);
  out[i] = o > 0.f ? o : expm1f(o);
}

extern "C" void kernel_launch(void* const* d_in, const int* in_sizes, int n_in,
                              void* d_out, int out_size, void* d_ws, size_t ws_size,
                              hipStream_t stream) {
  const float* x    = (const float*)d_in[0];
  const int*   ei   = (const int*)d_in[1];
  const float* ea   = (const float*)d_in[2];
  const int*   batch= (const int*)d_in[3];
  const float* Wl   = (const float*)d_in[4];
  const float* bl   = (const float*)d_in[5];
  const float* Wr   = (const float*)d_in[6];
  const float* br   = (const float*)d_in[7];
  const float* We   = (const float*)d_in[8];
  const float* att  = (const float*)d_in[9];
  const float* bias = (const float*)d_in[10];
  const float* gnw  = (const float*)d_in[11];
  const float* gnb  = (const float*)d_in[12];
  const float* gms  = (const float*)d_in[13];
  int N = in_sizes[0] / HC;
  int E = in_sizes[2] / EDIM;
  float* out = (float*)d_out;
  (void)n_in; (void)out_size; (void)ws_size;

  // ---- workspace carve-up (4-byte words, 16B aligned blocks) ----
  float* wsf = (float*)d_ws;
  size_t off = 0;
  auto alloc = [&](size_t words) -> float* {
    float* p = wsf + off;
    off += (words + 3) & ~(size_t)3;
    return p;
  };
  int*      deg     = (int*)alloc(N);
  int*      cursor  = (int*)alloc(N);
  int*      gcnt    = (int*)alloc(NG);
  float*    gsum    = alloc(NG * HC);
  float*    gsq     = alloc(NG * HC);
  size_t zero_words = off;                 // everything above starts at 0
  float*    msub    = alloc(NG * HC);
  float*    istd    = alloc(NG * HC);
  int*      bsum    = (int*)alloc(256);
  int*      bofs    = (int*)alloc(256);
  int*      offsets = (int*)alloc((size_t)N + 1);
  float*    xl      = alloc((size_t)N * HC);
  float*    xr      = alloc((size_t)N * HC);
  int*      csr     = (int*)alloc(E);

  int nb = (N + 255) / 256;   // scan blocks (<=256 by construction for N<=65536)

  zero_k<<<(unsigned)((zero_words + 255) / 256), 256, 0, stream>>>(wsf, zero_words);
  count_deg<<<(E + 255) / 256, 256, 0, stream>>>(ei, deg, E);
  gemm_xw<<<(N + 7) / 8, 256, 0, stream>>>(x, Wl, bl, xl, N);
  gemm_xw<<<(N + 7) / 8, 256, 0, stream>>>(x, Wr, br, xr, N);
  scan1<<<nb, 256, 0, stream>>>(deg, bsum, N);
  scan2<<<1, 1, 0, stream>>>(bsum, bofs, nb, offsets, N);
  scan3<<<nb, 256, 0, stream>>>(deg, bofs, offsets, N);
  fill_csr<<<(E + 255) / 256, 256, 0, stream>>>(ei, cursor, offsets, csr, E);
  fused_node<<<N, 128, 0, stream>>>(offsets, csr, ei, ea, xl, xr, We, att, x, bias, out, N, E);
  gn_stats<<<(N + GN_NODES - 1) / GN_NODES, 128, 0, stream>>>(out, batch, gsum, gsq, gcnt, N);
  gn_finalize<<<(NG * HC + 255) / 256, 256, 0, stream>>>(gsum, gsq, gcnt, gms, msub, istd);
  {
    long tot = (long)N * HC;
    gn_apply<<<(unsigned)((tot + 255) / 256), 256, 0, stream>>>(out, batch, msub, istd, gnw, gnb, N);
  }
}

// Round 3
// 576.854 us; speedup vs baseline: 1.8207x; 1.1016x over previous
//
#include <hip/hip_runtime.h>

#define HC 128          // H*C = output dim
#define HEADS 8
#define CPH 16
#define EDIM 16
#define NG 8
#define GEPS 1e-5f
#define LOG2E 1.44269504f

// ---------- K0: zero scratch ----------
__global__ void zero_k(float* __restrict__ p, size_t nwords) {
  size_t i = (size_t)blockIdx.x * 256 + threadIdx.x;
  if (i < nwords) p[i] = 0.f;
}

// ---------- K1: degree of real edges (by dst) + group-boundary marks ----------
__global__ void count_deg_mark(const int* __restrict__ ei, int* __restrict__ deg,
                               const int* __restrict__ batch, int* __restrict__ genc,
                               int E, int N) {
  int e = blockIdx.x * 256 + threadIdx.x;
  if (e >= E) return;
  atomicAdd(&deg[ei[E + e]], 1);
  if (e < N && (e == 0 || batch[e] != batch[e - 1])) {
    // encode start index i as (N - i) so zero-init means "empty group"
    atomicMax(&genc[batch[e]], N - e);
  }
}

// ---------- K2: xl = x@Wl+bl, xr = x@Wr+br in one pass ----------
// block 256 threads: 8 rows x 32 float4-column-groups
__global__ void __launch_bounds__(256) gemm_xw2(
    const float* __restrict__ x,
    const float* __restrict__ Wl, const float* __restrict__ bl,
    const float* __restrict__ Wr, const float* __restrict__ br,
    float* __restrict__ xl, float* __restrict__ xr, int N) {
  int t = threadIdx.x;
  int c4 = t & 31;          // float4 column group (4 channels)
  int rl = t >> 5;          // 0..7 local row
  long row = (long)blockIdx.x * 8 + rl;
  if (row >= N) return;
  const float4* Wl4 = (const float4*)Wl;        // [128][32] of float4
  const float4* Wr4 = (const float4*)Wr;
  const float4* x4 = (const float4*)(x + row * HC);
  float4 accl = ((const float4*)bl)[c4];
  float4 accr = ((const float4*)br)[c4];
  #pragma unroll 4
  for (int k4 = 0; k4 < 32; ++k4) {
    float4 xv = x4[k4];
    #pragma unroll
    for (int kk = 0; kk < 4; ++kk) {
      float xs = (&xv.x)[kk];
      float4 wl = Wl4[(k4 * 4 + kk) * 32 + c4];
      float4 wr = Wr4[(k4 * 4 + kk) * 32 + c4];
      accl.x = fmaf(xs, wl.x, accl.x); accl.y = fmaf(xs, wl.y, accl.y);
      accl.z = fmaf(xs, wl.z, accl.z); accl.w = fmaf(xs, wl.w, accl.w);
      accr.x = fmaf(xs, wr.x, accr.x); accr.y = fmaf(xs, wr.y, accr.y);
      accr.z = fmaf(xs, wr.z, accr.z); accr.w = fmaf(xs, wr.w, accr.w);
    }
  }
  ((float4*)(xl + row * HC))[c4] = accl;
  ((float4*)(xr + row * HC))[c4] = accr;
}

// ---------- K3: scan of deg -> offsets (CSR) ----------
__global__ void scan1(const int* __restrict__ deg, int* __restrict__ bsum, int N) {
  __shared__ int s[256];
  int t = threadIdx.x;
  int n = blockIdx.x * 256 + t;
  s[t] = (n < N) ? deg[n] : 0;
  __syncthreads();
  for (int off = 128; off > 0; off >>= 1) {
    if (t < off) s[t] += s[t + off];
    __syncthreads();
  }
  if (t == 0) bsum[blockIdx.x] = s[0];
}
__global__ void scan2(const int* __restrict__ bsum, int* __restrict__ bofs, int nb,
                      int* __restrict__ offsets, int N,
                      const int* __restrict__ genc, int* __restrict__ gstart) {
  int run = 0;
  for (int b = 0; b < nb; ++b) { bofs[b] = run; run += bsum[b]; }
  offsets[N] = run;
  // decode group starts; suffix-min so empty groups collapse to 0-length
  int nxt = N;
  gstart[NG] = N;
  for (int g = NG - 1; g >= 0; --g) {
    int st = N - genc[g];
    if (st > nxt) st = nxt;
    gstart[g] = st;
    nxt = st;
  }
}
__global__ void scan3(const int* __restrict__ deg, const int* __restrict__ bofs,
                      int* __restrict__ offsets, int N) {
  __shared__ int s[256];
  int t = threadIdx.x;
  int n = blockIdx.x * 256 + t;
  int v = (n < N) ? deg[n] : 0;
  s[t] = v;
  __syncthreads();
  for (int off = 1; off < 256; off <<= 1) {
    int add = (t >= off) ? s[t - off] : 0;
    __syncthreads();
    s[t] += add;
    __syncthreads();
  }
  if (n < N) offsets[n] = bofs[blockIdx.x] + s[t] - v;  // exclusive
}

// ---------- K4: fill CSR with (edge, src) pairs; consumes deg ----------
__global__ void fill_csr(const int* __restrict__ ei, int* __restrict__ deg,
                         const int* __restrict__ offsets, int2* __restrict__ csr2, int E) {
  int e = blockIdx.x * 256 + threadIdx.x;
  if (e >= E) return;
  int d = ei[E + e];
  int pos = atomicSub(&deg[d], 1) - 1;
  csr2[offsets[d] + pos] = make_int2(e, ei[e]);
}

// ---------- K5: FUSED per-node attention + defer-max online softmax + agg ----------
// One 128-thread block per destination node. Self-loop (ea fill 'mean') merged
// at the end: ea_mean . We[:,ch] == mean over edges of (ea[e] . We[:,ch]).
// Logits kept in log2 space (att pre-scaled by log2e) so exp == v_exp_f32.
__global__ void __launch_bounds__(128) fused_node(
    const int* __restrict__ offsets, const int2* __restrict__ csr2,
    const float* __restrict__ ea,
    const float* __restrict__ xl, const float* __restrict__ xr,
    const float* __restrict__ We, const float* __restrict__ att,
    const float* __restrict__ x, const float* __restrict__ bias,
    float* __restrict__ out, int N) {
  int ch = threadIdx.x;
  long n = blockIdx.x;
  float we[EDIM];
  #pragma unroll
  for (int k = 0; k < EDIM; ++k) we[k] = We[k * HC + ch];
  float av = att[ch] * LOG2E;
  float av08 = 0.8f * av, av02 = 0.2f * av;
  float xl_n = xl[n * HC + ch];
  float xr_n = xr[n * HC + ch];
  int j0 = offsets[n], j1 = offsets[n + 1];

  float m = -INFINITY;   // running max (log2 space), uniform per 16-lane head
  float den = 0.f;       // running softmax denominator
  float acc = 0.f;       // running weighted feature sum (per channel)
  float eesum = 0.f;     // per-channel sum of (eev + xr_n); adjusted at end

  for (int j = j0; j < j1; ++j) {
    int2 es = csr2[j];
    int e = __builtin_amdgcn_readfirstlane(es.x);
    int s = __builtin_amdgcn_readfirstlane(es.y);
    float xls = xl[(long)s * HC + ch];
    const float4* eap = (const float4*)(ea + (long)e * EDIM);
    float4 a0 = eap[0], a1 = eap[1], a2 = eap[2], a3 = eap[3];
    float mm = xr_n;
    mm = fmaf(a0.x, we[0], mm);  mm = fmaf(a0.y, we[1], mm);
    mm = fmaf(a0.z, we[2], mm);  mm = fmaf(a0.w, we[3], mm);
    mm = fmaf(a1.x, we[4], mm);  mm = fmaf(a1.y, we[5], mm);
    mm = fmaf(a1.z, we[6], mm);  mm = fmaf(a1.w, we[7], mm);
    mm = fmaf(a2.x, we[8], mm);  mm = fmaf(a2.y, we[9], mm);
    mm = fmaf(a2.z, we[10], mm); mm = fmaf(a2.w, we[11], mm);
    mm = fmaf(a3.x, we[12], mm); mm = fmaf(a3.y, we[13], mm);
    mm = fmaf(a3.z, we[14], mm); mm = fmaf(a3.w, we[15], mm);
    eesum += mm;                       // = eev + xr_n
    mm += xls;
    float p = fmaf(av08, fmaxf(mm, 0.f), av02 * mm);  // leaky(mm)*att*log2e
    p += __shfl_xor(p, 8);
    p += __shfl_xor(p, 4);
    p += __shfl_xor(p, 2);
    p += __shfl_xor(p, 1);             // head logit, uniform in 16-lane group
    if (p > m + 11.5f) {               // rare: new max grew past threshold
      float sc = exp2f(m - p);
      acc = fmaf(acc, sc, xls);
      den = fmaf(den, sc, 1.f);
      m = p;
    } else {                           // common: single exp2, no rescale
      float w = exp2f(p - m);
      acc = fmaf(w, xls, acc);
      den += w;
    }
  }

  // ---- self-loop ----
  int deg = j1 - j0;
  float ee = (deg > 0) ? (eesum / (float)deg - xr_n) : 0.f;
  float mm = xl_n + xr_n + ee;
  float p = fmaf(av08, fmaxf(mm, 0.f), av02 * mm);
  p += __shfl_xor(p, 8);
  p += __shfl_xor(p, 4);
  p += __shfl_xor(p, 2);
  p += __shfl_xor(p, 1);
  if (p > m) {
    float sc = exp2f(m - p);
    acc = fmaf(acc, sc, xl_n);
    den = fmaf(den, sc, 1.f);
  } else {
    float w = exp2f(p - m);
    acc = fmaf(w, xl_n, acc);
    den += w;
  }

  out[n * HC + ch] = acc / den + bias[ch] + x[n * HC + ch];
}

// ---------- K6: GraphNorm segment sums (grid-parallel over group slices) ----------
#define GN_SLICES 32
__global__ void __launch_bounds__(128) gn_stats(
    const float* __restrict__ out, const int* __restrict__ gstart,
    float* __restrict__ gsum, float* __restrict__ gsq) {
  int g = blockIdx.x >> 5;
  int slice = blockIdx.x & 31;
  int s0 = gstart[g], s1 = gstart[g + 1];
  int cnt = s1 - s0;
  if (cnt <= 0) return;
  int chunk = (cnt + GN_SLICES - 1) / GN_SLICES;
  int lo = s0 + slice * chunk;
  int hi = lo + chunk; if (hi > s1) hi = s1;
  if (lo >= hi) return;
  int ch = threadIdx.x;
  float sum = 0.f, sq = 0.f;
  for (int nrow = lo; nrow < hi; ++nrow) {
    float v = out[(long)nrow * HC + ch];
    sum += v; sq += v * v;
  }
  atomicAdd(&gsum[g * HC + ch], sum);
  atomicAdd(&gsq[g * HC + ch], sq);
}

// ---------- K7: finalize mean / inv-std ----------
__global__ void gn_finalize(const float* __restrict__ gsum, const float* __restrict__ gsq,
                            const int* __restrict__ gstart, const float* __restrict__ gms,
                            float* __restrict__ msub, float* __restrict__ istd) {
  int t = blockIdx.x * 256 + threadIdx.x;
  if (t >= NG * HC) return;
  int g = t >> 7, ch = t & 127;
  float cnt = (float)(gstart[g + 1] - gstart[g]);
  if (cnt < 1.f) cnt = 1.f;
  float mean = gsum[t] / cnt;
  float c = gms[ch] * mean;              // the subtracted constant
  float ex2 = gsq[t] / cnt;
  float var = ex2 - 2.f * c * mean + c * c;   // E[(x-c)^2]
  msub[t] = c;
  istd[t] = rsqrtf(var + GEPS);
}

// ---------- K8: normalize + affine + ELU (float4) ----------
__global__ void gn_apply(float* __restrict__ out, const int* __restrict__ batch,
                         const float* __restrict__ msub, const float* __restrict__ istd,
                         const float* __restrict__ gnw, const float* __restrict__ gnb, int N) {
  long i = (long)blockIdx.x * 256 + threadIdx.x;     // float4 index
  if (i >= (long)N * 32) return;
  int c4 = (int)(i & 31);
  long n = i >> 5;
  int g = batch[n];
  float4 v = ((const float4*)out)[i];
  float4 ms = ((const float4*)msub)[g * 32 + c4];
  float4 is = ((const float4*)istd)[g * 32 + c4];
  float4 w  = ((const float4*)gnw)[c4];
  float4 b  = ((const float4*)gnb)[c4];
  float4 o;
  o.x = fmaf(w.x * (v.x - ms.x), is.x, b.x);
  o.y = fmaf(w.y * (v.y - ms.y), is.y, b.y);
  o.z = fmaf(w.z * (v.z - ms.z), is.z, b.z);
  o.w = fmaf(w.w * (v.w - ms.w), is.w, b.w);
  o.x = o.x > 0.f ? o.x : expm1f(o.x);
  o.y = o.y > 0.f ? o.y : expm1f(o.y);
  o.z = o.z > 0.f ? o.z : expm1f(o.z);
  o.w = o.w > 0.f ? o.w : expm1f(o.w);
  ((float4*)out)[i] = o;
}

extern "C" void kernel_launch(void* const* d_in, const int* in_sizes, int n_in,
                              void* d_out, int out_size, void* d_ws, size_t ws_size,
                              hipStream_t stream) {
  const float* x    = (const float*)d_in[0];
  const int*   ei   = (const int*)d_in[1];
  const float* ea   = (const float*)d_in[2];
  const int*   batch= (const int*)d_in[3];
  const float* Wl   = (const float*)d_in[4];
  const float* bl   = (const float*)d_in[5];
  const float* Wr   = (const float*)d_in[6];
  const float* br   = (const float*)d_in[7];
  const float* We   = (const float*)d_in[8];
  const float* att  = (const float*)d_in[9];
  const float* bias = (const float*)d_in[10];
  const float* gnw  = (const float*)d_in[11];
  const float* gnb  = (const float*)d_in[12];
  const float* gms  = (const float*)d_in[13];
  int N = in_sizes[0] / HC;
  int E = in_sizes[2] / EDIM;
  float* out = (float*)d_out;
  (void)n_in; (void)out_size; (void)ws_size;

  // ---- workspace carve-up (4-byte words, 16B aligned blocks) ----
  float* wsf = (float*)d_ws;
  size_t off = 0;
  auto alloc = [&](size_t words) -> float* {
    float* p = wsf + off;
    off += (words + 3) & ~(size_t)3;
    return p;
  };
  int*      deg     = (int*)alloc(N);
  float*    gsum    = alloc(NG * HC);
  float*    gsq     = alloc(NG * HC);
  int*      genc    = (int*)alloc(NG);
  size_t zero_words = off;                 // everything above starts at 0
  int*      gstart  = (int*)alloc(NG + 1);
  float*    msub    = alloc(NG * HC);
  float*    istd    = alloc(NG * HC);
  int*      bsum    = (int*)alloc(256);
  int*      bofs    = (int*)alloc(256);
  int*      offsets = (int*)alloc((size_t)N + 1);
  float*    xl      = alloc((size_t)N * HC);
  float*    xr      = alloc((size_t)N * HC);
  int2*     csr2    = (int2*)alloc((size_t)E * 2);

  int nb = (N + 255) / 256;   // scan blocks (<=256 by construction for N<=65536)

  zero_k<<<(unsigned)((zero_words + 255) / 256), 256, 0, stream>>>(wsf, zero_words);
  count_deg_mark<<<(E + 255) / 256, 256, 0, stream>>>(ei, deg, batch, genc, E, N);
  gemm_xw2<<<(N + 7) / 8, 256, 0, stream>>>(x, Wl, bl, Wr, br, xl, xr, N);
  scan1<<<nb, 256, 0, stream>>>(deg, bsum, N);
  scan2<<<1, 1, 0, stream>>>(bsum, bofs, nb, offsets, N, genc, gstart);
  scan3<<<nb, 256, 0, stream>>>(deg, bofs, offsets, N);
  fill_csr<<<(E + 255) / 256, 256, 0, stream>>>(ei, deg, offsets, csr2, E);
  fused_node<<<N, 128, 0, stream>>>(offsets, csr2, ea, xl, xr, We, att, x, bias, out, N);
  gn_stats<<<NG * GN_SLICES, 128, 0, stream>>>(out, gstart, gsum, gsq);
  gn_finalize<<<(NG * HC + 255) / 256, 256, 0, stream>>>(gsum, gsq, gstart, gms, msub, istd);
  {
    long tot = (long)N * 32;
    gn_apply<<<(unsigned)((tot + 255) / 256), 256, 0, stream>>>(out, batch, msub, istd, gnw, gnb, N);
  }
}

// Round 4
// 545.678 us; speedup vs baseline: 1.9247x; 1.0571x over previous
//
#include <hip/hip_runtime.h>

#define HC 128          // H*C = output dim
#define HEADS 8
#define CPH 16
#define EDIM 16
#define NG 8
#define GEPS 1e-5f
#define LOG2E 1.44269504f

// ---------- 16-lane (head) sum via DPP row rotates: pure VALU, no LDS ----------
__device__ __forceinline__ float head16_sum(float p) {
  int t;
  t = __builtin_amdgcn_update_dpp(0, __float_as_int(p), 0x128, 0xF, 0xF, true); // row_ror:8
  p += __int_as_float(t);
  t = __builtin_amdgcn_update_dpp(0, __float_as_int(p), 0x124, 0xF, 0xF, true); // row_ror:4
  p += __int_as_float(t);
  t = __builtin_amdgcn_update_dpp(0, __float_as_int(p), 0x122, 0xF, 0xF, true); // row_ror:2
  p += __int_as_float(t);
  t = __builtin_amdgcn_update_dpp(0, __float_as_int(p), 0x121, 0xF, 0xF, true); // row_ror:1
  p += __int_as_float(t);
  return p;
}

// ---------- K0: zero scratch ----------
__global__ void zero_k(float* __restrict__ p, size_t nwords) {
  size_t i = (size_t)blockIdx.x * 256 + threadIdx.x;
  if (i < nwords) p[i] = 0.f;
}

// ---------- K1: degree of real edges (by dst) + group-boundary marks ----------
__global__ void count_deg_mark(const int* __restrict__ ei, int* __restrict__ deg,
                               const int* __restrict__ batch, int* __restrict__ genc,
                               int E, int N) {
  int e = blockIdx.x * 256 + threadIdx.x;
  if (e >= E) return;
  atomicAdd(&deg[ei[E + e]], 1);
  if (e < N && (e == 0 || batch[e] != batch[e - 1])) {
    // encode start index i as (N - i) so zero-init means "empty group"
    atomicMax(&genc[batch[e]], N - e);
  }
}

// ---------- K2: xl = x@Wl+bl, xr = x@Wr+br in one pass ----------
// block 256 threads: 16 rows x 16 col-threads, 2 float4 col-groups per thread
__global__ void __launch_bounds__(256) gemm_xw2(
    const float* __restrict__ x,
    const float* __restrict__ Wl, const float* __restrict__ bl,
    const float* __restrict__ Wr, const float* __restrict__ br,
    float* __restrict__ xl, float* __restrict__ xr, int N) {
  int t = threadIdx.x;
  int cA = t & 15;          // float4 column group A (B = A+16)
  int rl = t >> 4;          // 0..15 local row
  long row = (long)blockIdx.x * 16 + rl;
  if (row >= N) return;
  const float4* Wl4 = (const float4*)Wl;        // [128][32] of float4
  const float4* Wr4 = (const float4*)Wr;
  const float4* x4 = (const float4*)(x + row * HC);
  float4 accl0 = ((const float4*)bl)[cA];
  float4 accl1 = ((const float4*)bl)[cA + 16];
  float4 accr0 = ((const float4*)br)[cA];
  float4 accr1 = ((const float4*)br)[cA + 16];
  #pragma unroll 4
  for (int k4 = 0; k4 < 32; ++k4) {
    float4 xv = x4[k4];
    #pragma unroll
    for (int kk = 0; kk < 4; ++kk) {
      float xs = (&xv.x)[kk];
      int ki = (k4 * 4 + kk) * 32;
      float4 wl0 = Wl4[ki + cA], wl1 = Wl4[ki + cA + 16];
      float4 wr0 = Wr4[ki + cA], wr1 = Wr4[ki + cA + 16];
      accl0.x = fmaf(xs, wl0.x, accl0.x); accl0.y = fmaf(xs, wl0.y, accl0.y);
      accl0.z = fmaf(xs, wl0.z, accl0.z); accl0.w = fmaf(xs, wl0.w, accl0.w);
      accl1.x = fmaf(xs, wl1.x, accl1.x); accl1.y = fmaf(xs, wl1.y, accl1.y);
      accl1.z = fmaf(xs, wl1.z, accl1.z); accl1.w = fmaf(xs, wl1.w, accl1.w);
      accr0.x = fmaf(xs, wr0.x, accr0.x); accr0.y = fmaf(xs, wr0.y, accr0.y);
      accr0.z = fmaf(xs, wr0.z, accr0.z); accr0.w = fmaf(xs, wr0.w, accr0.w);
      accr1.x = fmaf(xs, wr1.x, accr1.x); accr1.y = fmaf(xs, wr1.y, accr1.y);
      accr1.z = fmaf(xs, wr1.z, accr1.z); accr1.w = fmaf(xs, wr1.w, accr1.w);
    }
  }
  ((float4*)(xl + row * HC))[cA]      = accl0;
  ((float4*)(xl + row * HC))[cA + 16] = accl1;
  ((float4*)(xr + row * HC))[cA]      = accr0;
  ((float4*)(xr + row * HC))[cA + 16] = accr1;
}

// ---------- K3: scan of deg -> offsets (CSR) ----------
__global__ void scan1(const int* __restrict__ deg, int* __restrict__ bsum, int N) {
  __shared__ int s[256];
  int t = threadIdx.x;
  int n = blockIdx.x * 256 + t;
  s[t] = (n < N) ? deg[n] : 0;
  __syncthreads();
  for (int off = 128; off > 0; off >>= 1) {
    if (t < off) s[t] += s[t + off];
    __syncthreads();
  }
  if (t == 0) bsum[blockIdx.x] = s[0];
}
__global__ void scan2(const int* __restrict__ bsum, int* __restrict__ bofs, int nb,
                      int* __restrict__ offsets, int N,
                      const int* __restrict__ genc, int* __restrict__ gstart) {
  int run = 0;
  for (int b = 0; b < nb; ++b) { bofs[b] = run; run += bsum[b]; }
  offsets[N] = run;
  // decode group starts; suffix-min so empty groups collapse to 0-length
  int nxt = N;
  gstart[NG] = N;
  for (int g = NG - 1; g >= 0; --g) {
    int st = N - genc[g];
    if (st > nxt) st = nxt;
    gstart[g] = st;
    nxt = st;
  }
}
__global__ void scan3(const int* __restrict__ deg, const int* __restrict__ bofs,
                      int* __restrict__ offsets, int N) {
  __shared__ int s[256];
  int t = threadIdx.x;
  int n = blockIdx.x * 256 + t;
  int v = (n < N) ? deg[n] : 0;
  s[t] = v;
  __syncthreads();
  for (int off = 1; off < 256; off <<= 1) {
    int add = (t >= off) ? s[t - off] : 0;
    __syncthreads();
    s[t] += add;
    __syncthreads();
  }
  if (n < N) offsets[n] = bofs[blockIdx.x] + s[t] - v;  // exclusive
}

// ---------- K4: fill CSR with (edge, src) pairs; consumes deg ----------
__global__ void fill_csr(const int* __restrict__ ei, int* __restrict__ deg,
                         const int* __restrict__ offsets, int2* __restrict__ csr2, int E) {
  int e = blockIdx.x * 256 + threadIdx.x;
  if (e >= E) return;
  int d = ei[E + e];
  int pos = atomicSub(&deg[d], 1) - 1;
  csr2[offsets[d] + pos] = make_int2(e, ei[e]);
}

// ---------- K5: FUSED per-node attention + defer-max online softmax + agg ----------
// One 128-thread block per destination node. Self-loop (ea fill 'mean') merged
// at the end: ea_mean . We[:,ch] == mean over edges of (ea[e] . We[:,ch]).
// Logits kept in log2 space (att pre-scaled by log2e) so exp == v_exp_f32.
__global__ void __launch_bounds__(128) fused_node(
    const int* __restrict__ offsets, const int2* __restrict__ csr2,
    const float* __restrict__ ea,
    const float* __restrict__ xl, const float* __restrict__ xr,
    const float* __restrict__ We, const float* __restrict__ att,
    const float* __restrict__ x, const float* __restrict__ bias,
    float* __restrict__ out, int N) {
  int ch = threadIdx.x;
  long n = blockIdx.x;
  float we[EDIM];
  #pragma unroll
  for (int k = 0; k < EDIM; ++k) we[k] = We[k * HC + ch];
  float av = att[ch] * LOG2E;
  float av08 = 0.8f * av, av02 = 0.2f * av;
  float xl_n = xl[n * HC + ch];
  float xr_n = xr[n * HC + ch];
  int j0 = offsets[n], j1 = offsets[n + 1];

  float m = -INFINITY;   // running max (log2 space), uniform per 16-lane head
  float den = 0.f;       // running softmax denominator
  float acc = 0.f;       // running weighted feature sum (per channel)
  float eesum = 0.f;     // per-channel sum of (eev + xr_n); adjusted at end

  auto edge_update = [&](int e, float xls) {
    const float4* eap = (const float4*)(ea + (long)e * EDIM);
    float4 a0 = eap[0], a1 = eap[1], a2 = eap[2], a3 = eap[3];
    float mm = xr_n;
    mm = fmaf(a0.x, we[0], mm);  mm = fmaf(a0.y, we[1], mm);
    mm = fmaf(a0.z, we[2], mm);  mm = fmaf(a0.w, we[3], mm);
    mm = fmaf(a1.x, we[4], mm);  mm = fmaf(a1.y, we[5], mm);
    mm = fmaf(a1.z, we[6], mm);  mm = fmaf(a1.w, we[7], mm);
    mm = fmaf(a2.x, we[8], mm);  mm = fmaf(a2.y, we[9], mm);
    mm = fmaf(a2.z, we[10], mm); mm = fmaf(a2.w, we[11], mm);
    mm = fmaf(a3.x, we[12], mm); mm = fmaf(a3.y, we[13], mm);
    mm = fmaf(a3.z, we[14], mm); mm = fmaf(a3.w, we[15], mm);
    eesum += mm;                       // = eev + xr_n
    mm += xls;
    float p = fmaf(av08, fmaxf(mm, 0.f), av02 * mm);  // leaky(mm)*att*log2e
    p = head16_sum(p);                 // head logit, uniform in 16-lane group
    if (p > m + 11.5f) {               // rare: new max grew past threshold
      float sc = exp2f(m - p);
      acc = fmaf(acc, sc, xls);
      den = fmaf(den, sc, 1.f);
      m = p;
    } else {                           // common: single exp2, no rescale
      float w = exp2f(p - m);
      acc = fmaf(w, xls, acc);
      den += w;
    }
  };

  int j = j0;
  if ((j & 1) && j < j1) {             // peel to 16B-aligned pair boundary
    int2 es = csr2[j];
    int e = __builtin_amdgcn_readfirstlane(es.x);
    int s = __builtin_amdgcn_readfirstlane(es.y);
    edge_update(e, xl[(long)s * HC + ch]);
    ++j;
  }
  for (; j + 1 < j1; j += 2) {
    int4 q = *(const int4*)(csr2 + j);  // two (edge,src) pairs, one dwordx4
    int e0 = __builtin_amdgcn_readfirstlane(q.x);
    int s0 = __builtin_amdgcn_readfirstlane(q.y);
    int e1 = __builtin_amdgcn_readfirstlane(q.z);
    int s1 = __builtin_amdgcn_readfirstlane(q.w);
    float xls0 = xl[(long)s0 * HC + ch];
    float xls1 = xl[(long)s1 * HC + ch];
    edge_update(e0, xls0);
    edge_update(e1, xls1);
  }
  if (j < j1) {
    int2 es = csr2[j];
    int e = __builtin_amdgcn_readfirstlane(es.x);
    int s = __builtin_amdgcn_readfirstlane(es.y);
    edge_update(e, xl[(long)s * HC + ch]);
  }

  // ---- self-loop ----
  int deg = j1 - j0;
  float ee = (deg > 0) ? (eesum / (float)deg - xr_n) : 0.f;
  float mm = xl_n + xr_n + ee;
  float p = fmaf(av08, fmaxf(mm, 0.f), av02 * mm);
  p = head16_sum(p);
  if (p > m) {
    float sc = exp2f(m - p);
    acc = fmaf(acc, sc, xl_n);
    den = fmaf(den, sc, 1.f);
  } else {
    float w = exp2f(p - m);
    acc = fmaf(w, xl_n, acc);
    den += w;
  }

  out[n * HC + ch] = acc / den + bias[ch] + x[n * HC + ch];
}

// ---------- K6: GraphNorm segment sums (grid-parallel over group slices) ----------
#define GN_SLICES 32
__global__ void __launch_bounds__(128) gn_stats(
    const float* __restrict__ out, const int* __restrict__ gstart,
    float* __restrict__ gsum, float* __restrict__ gsq) {
  int g = blockIdx.x >> 5;
  int slice = blockIdx.x & 31;
  int s0 = gstart[g], s1 = gstart[g + 1];
  int cnt = s1 - s0;
  if (cnt <= 0) return;
  int chunk = (cnt + GN_SLICES - 1) / GN_SLICES;
  int lo = s0 + slice * chunk;
  int hi = lo + chunk; if (hi > s1) hi = s1;
  if (lo >= hi) return;
  int ch = threadIdx.x;
  float sum = 0.f, sq = 0.f;
  for (int nrow = lo; nrow < hi; ++nrow) {
    float v = out[(long)nrow * HC + ch];
    sum += v; sq += v * v;
  }
  atomicAdd(&gsum[g * HC + ch], sum);
  atomicAdd(&gsq[g * HC + ch], sq);
}

// ---------- K7: finalize mean / inv-std ----------
__global__ void gn_finalize(const float* __restrict__ gsum, const float* __restrict__ gsq,
                            const int* __restrict__ gstart, const float* __restrict__ gms,
                            float* __restrict__ msub, float* __restrict__ istd) {
  int t = blockIdx.x * 256 + threadIdx.x;
  if (t >= NG * HC) return;
  int g = t >> 7, ch = t & 127;
  float cnt = (float)(gstart[g + 1] - gstart[g]);
  if (cnt < 1.f) cnt = 1.f;
  float mean = gsum[t] / cnt;
  float c = gms[ch] * mean;              // the subtracted constant
  float ex2 = gsq[t] / cnt;
  float var = ex2 - 2.f * c * mean + c * c;   // E[(x-c)^2]
  msub[t] = c;
  istd[t] = rsqrtf(var + GEPS);
}

// ---------- K8: normalize + affine + ELU (float4) ----------
__global__ void gn_apply(float* __restrict__ out, const int* __restrict__ batch,
                         const float* __restrict__ msub, const float* __restrict__ istd,
                         const float* __restrict__ gnw, const float* __restrict__ gnb, int N) {
  long i = (long)blockIdx.x * 256 + threadIdx.x;     // float4 index
  if (i >= (long)N * 32) return;
  int c4 = (int)(i & 31);
  long n = i >> 5;
  int g = batch[n];
  float4 v = ((const float4*)out)[i];
  float4 ms = ((const float4*)msub)[g * 32 + c4];
  float4 is = ((const float4*)istd)[g * 32 + c4];
  float4 w  = ((const float4*)gnw)[c4];
  float4 b  = ((const float4*)gnb)[c4];
  float4 o;
  o.x = fmaf(w.x * (v.x - ms.x), is.x, b.x);
  o.y = fmaf(w.y * (v.y - ms.y), is.y, b.y);
  o.z = fmaf(w.z * (v.z - ms.z), is.z, b.z);
  o.w = fmaf(w.w * (v.w - ms.w), is.w, b.w);
  o.x = o.x > 0.f ? o.x : expm1f(o.x);
  o.y = o.y > 0.f ? o.y : expm1f(o.y);
  o.z = o.z > 0.f ? o.z : expm1f(o.z);
  o.w = o.w > 0.f ? o.w : expm1f(o.w);
  ((float4*)out)[i] = o;
}

extern "C" void kernel_launch(void* const* d_in, const int* in_sizes, int n_in,
                              void* d_out, int out_size, void* d_ws, size_t ws_size,
                              hipStream_t stream) {
  const float* x    = (const float*)d_in[0];
  const int*   ei   = (const int*)d_in[1];
  const float* ea   = (const float*)d_in[2];
  const int*   batch= (const int*)d_in[3];
  const float* Wl   = (const float*)d_in[4];
  const float* bl   = (const float*)d_in[5];
  const float* Wr   = (const float*)d_in[6];
  const float* br   = (const float*)d_in[7];
  const float* We   = (const float*)d_in[8];
  const float* att  = (const float*)d_in[9];
  const float* bias = (const float*)d_in[10];
  const float* gnw  = (const float*)d_in[11];
  const float* gnb  = (const float*)d_in[12];
  const float* gms  = (const float*)d_in[13];
  int N = in_sizes[0] / HC;
  int E = in_sizes[2] / EDIM;
  float* out = (float*)d_out;
  (void)n_in; (void)out_size; (void)ws_size;

  // ---- workspace carve-up (4-byte words, 16B aligned blocks) ----
  float* wsf = (float*)d_ws;
  size_t off = 0;
  auto alloc = [&](size_t words) -> float* {
    float* p = wsf + off;
    off += (words + 3) & ~(size_t)3;
    return p;
  };
  int*      deg     = (int*)alloc(N);
  float*    gsum    = alloc(NG * HC);
  float*    gsq     = alloc(NG * HC);
  int*      genc    = (int*)alloc(NG);
  size_t zero_words = off;                 // everything above starts at 0
  int*      gstart  = (int*)alloc(NG + 1);
  float*    msub    = alloc(NG * HC);
  float*    istd    = alloc(NG * HC);
  int*      bsum    = (int*)alloc(256);
  int*      bofs    = (int*)alloc(256);
  int*      offsets = (int*)alloc((size_t)N + 1);
  float*    xl      = alloc((size_t)N * HC);
  float*    xr      = alloc((size_t)N * HC);
  int2*     csr2    = (int2*)alloc((size_t)E * 2);

  int nb = (N + 255) / 256;   // scan blocks (<=256 by construction for N<=65536)

  zero_k<<<(unsigned)((zero_words + 255) / 256), 256, 0, stream>>>(wsf, zero_words);
  count_deg_mark<<<(E + 255) / 256, 256, 0, stream>>>(ei, deg, batch, genc, E, N);
  gemm_xw2<<<(N + 15) / 16, 256, 0, stream>>>(x, Wl, bl, Wr, br, xl, xr, N);
  scan1<<<nb, 256, 0, stream>>>(deg, bsum, N);
  scan2<<<1, 1, 0, stream>>>(bsum, bofs, nb, offsets, N, genc, gstart);
  scan3<<<nb, 256, 0, stream>>>(deg, bofs, offsets, N);
  fill_csr<<<(E + 255) / 256, 256, 0, stream>>>(ei, deg, offsets, csr2, E);
  fused_node<<<N, 128, 0, stream>>>(offsets, csr2, ea, xl, xr, We, att, x, bias, out, N);
  gn_stats<<<NG * GN_SLICES, 128, 0, stream>>>(out, gstart, gsum, gsq);
  gn_finalize<<<(NG * HC + 255) / 256, 256, 0, stream>>>(gsum, gsq, gstart, gms, msub, istd);
  {
    long tot = (long)N * 32;
    gn_apply<<<(unsigned)((tot + 255) / 256), 256, 0, stream>>>(out, batch, msub, istd, gnw, gnb, N);
  }
}